// Round 17
// baseline (102.760 us; speedup 1.0000x reference)
//
#include <hip/hip_runtime.h>
#include <hip/hip_fp16.h>

#define N_NODES 50000
#define N_EDGES 800000
#define ETOT    (2 * N_EDGES + N_NODES)   // 1,650,000
#define F       64
#define NEG_SLOPE 0.2f
#define SCAN_B  1024
#define NB_S    ((N_NODES + SCAN_B - 1) / SCAN_B)   // 49 scan blocks

#define RSPLIT  4
#define NRANGE  (N_NODES / RSPLIT)        // 12500 nodes -> 50 KB LDS
#define CCHUNK  64
#define EPC     (N_EDGES / CCHUNK)        // 12500 edges per chunk
#define BLD     1024

#define XT_TASKS  (N_NODES / 16)          // 3125 wave-tasks, 16 nodes each
#define HIST_BLKS (CCHUNK * RSPLIT)       // 256
#define XT_BLKS   ((XT_TASKS + 15) / 16)  // 196 blocks of 16 waves

typedef _Float16 half8 __attribute__((ext_vector_type(8)));
typedef float    f32x4 __attribute__((ext_vector_type(4)));

__device__ __forceinline__ float leaky(float v) {
    return (v > 0.f) ? v : NEG_SLOPE * v;
}
// entry = src (low16) | fp16(exp(leaky(logit))) (high16)
__device__ __forceinline__ unsigned int pack_entry(int src, float w) {
    __half h = __float2half(w);
    return (unsigned int)(unsigned short)src |
           ((unsigned int)__half_as_ushort(h) << 16);
}
// XCD-aware (chunk,range) decode: same range r -> one XCD pair.
__device__ __forceinline__ void cr_decode(int bid, int& c, int& r) {
    const int m = bid & 7;
    r = m >> 1;
    c = ((bid >> 3) << 1) | (m & 1);
}

// ======== k_front: role-split. blocks [0,256): hist+ec. [256,452): MFMA xt ========
__global__ void __launch_bounds__(BLD) k_front(const float* __restrict__ x,
                                               const float* __restrict__ W,
                                               const float* __restrict__ a,
                                               const float* __restrict__ ea,
                                               const int* __restrict__ srcs,
                                               const int* __restrict__ dsts,
                                               __half* __restrict__ xt,
                                               float2* __restrict__ sd,
                                               __half* __restrict__ ec,
                                               unsigned short* __restrict__ cnt,
                                               unsigned long long* __restrict__ state) {
    __shared__ int h[NRANGE];
    if (blockIdx.x == 0 && threadIdx.x < NB_S) state[threadIdx.x] = 0ull;

    if (blockIdx.x < HIST_BLKS) {
        // ---- histogram + fused ec (fp16) ----
        int c, r;
        cr_decode(blockIdx.x, c, r);
        const int nbase = r * NRANGE;
        for (int i = threadIdx.x; i < NRANGE; i += BLD) h[i] = 0;
        __syncthreads();
        const int e0 = c * EPC;
        for (int i = e0 + threadIdx.x; i < e0 + EPC; i += BLD) {
            const int d = dsts[i] - nbase;
            if ((unsigned)d < NRANGE) atomicAdd(&h[d], 1);
            const int s = srcs[i] - nbase;
            if ((unsigned)s < NRANGE) atomicAdd(&h[s], 1);
        }
        const int eq0 = e0 + (r * EPC) / RSPLIT;
        const int eq1 = e0 + ((r + 1) * EPC) / RSPLIT;
        for (int i = eq0 + threadIdx.x; i < eq1; i += BLD) {
            const float4* p = (const float4*)(ea + (size_t)i * 16);
            float acc = 0.f;
#pragma unroll
            for (int k = 0; k < 4; ++k) {
                float4 v = p[k];
                acc += v.x * a[128 + k * 4 + 0] + v.y * a[128 + k * 4 + 1] +
                       v.z * a[128 + k * 4 + 2] + v.w * a[128 + k * 4 + 3];
            }
            ec[i] = __float2half(acc);
        }
        __syncthreads();
        unsigned short* o = cnt + (size_t)c * N_NODES + nbase;
        for (int i = threadIdx.x; i < NRANGE; i += BLD) o[i] = (unsigned short)h[i];
    } else {
        // ---- xt = x @ W via MFMA; one wave per 16-node task ----
        const int lane = threadIdx.x & 63;
        const int task = (blockIdx.x - HIST_BLKS) * 16 + (threadIdx.x >> 6);
        if (task >= XT_TASKS) return;
        const int n0  = task * 16;
        const int r16 = lane & 15;
        const int kb  = lane >> 4;

        half8 bf[4][2];
#pragma unroll
        for (int c = 0; c < 4; ++c)
#pragma unroll
            for (int ks = 0; ks < 2; ++ks) {
                const float* wp = W + (size_t)(ks * 32 + kb * 8) * 64 + c * 16 + r16;
#pragma unroll
                for (int j = 0; j < 8; ++j) bf[c][ks][j] = (_Float16)wp[j * 64];
            }

        half8 af[2];
#pragma unroll
        for (int ks = 0; ks < 2; ++ks) {
            const float* xp = x + (size_t)(n0 + r16) * F + ks * 32 + kb * 8;
            const float4 v0 = *(const float4*)xp;
            const float4 v1 = *(const float4*)(xp + 4);
            af[ks][0] = (_Float16)v0.x; af[ks][1] = (_Float16)v0.y;
            af[ks][2] = (_Float16)v0.z; af[ks][3] = (_Float16)v0.w;
            af[ks][4] = (_Float16)v1.x; af[ks][5] = (_Float16)v1.y;
            af[ks][6] = (_Float16)v1.z; af[ks][7] = (_Float16)v1.w;
        }

        f32x4 acc[4];
#pragma unroll
        for (int c = 0; c < 4; ++c) {
            acc[c] = (f32x4){0.f, 0.f, 0.f, 0.f};
            acc[c] = __builtin_amdgcn_mfma_f32_16x16x32_f16(af[0], bf[c][0], acc[c], 0, 0, 0);
            acc[c] = __builtin_amdgcn_mfma_f32_16x16x32_f16(af[1], bf[c][1], acc[c], 0, 0, 0);
        }

        float ps[4] = {0.f, 0.f, 0.f, 0.f};
        float pd[4] = {0.f, 0.f, 0.f, 0.f};
#pragma unroll
        for (int c = 0; c < 4; ++c) {
            const float as_ = a[c * 16 + r16];
            const float ad_ = a[64 + c * 16 + r16];
#pragma unroll
            for (int r = 0; r < 4; ++r) {
                const float v = acc[c][r];
                const int n = n0 + kb * 4 + r;
                xt[(size_t)n * F + c * 16 + r16] = __float2half(v);
                ps[r] = fmaf(v, as_, ps[r]);
                pd[r] = fmaf(v, ad_, pd[r]);
            }
        }
#pragma unroll
        for (int r = 0; r < 4; ++r) {
#pragma unroll
            for (int off = 1; off <= 8; off <<= 1) {
                ps[r] += __shfl_xor(ps[r], off);
                pd[r] += __shfl_xor(pd[r], off);
            }
        }
        if (r16 == 0) {
#pragma unroll
            for (int r = 0; r < 4; ++r) sd[n0 + kb * 4 + r] = make_float2(ps[r], pd[r]);
        }
    }
}

// ======== k_scan: chunk-prefix (in-place u16) + single-level lookback node scan ====
__global__ void k_scan(unsigned short* __restrict__ cnt,
                       const float2* __restrict__ sd,
                       int* __restrict__ offs,
                       unsigned int* __restrict__ csr,
                       unsigned long long* __restrict__ state) {
    __shared__ int wtot[16];
    __shared__ int wexc[16];
    __shared__ int sbase;
    const int tid = threadIdx.x, lane = tid & 63, wid = tid >> 6;
    const int bid = blockIdx.x;
    const int i = bid * SCAN_B + tid;
    int v = 0;
    if (i < N_NODES) {
        int run = 0;
#pragma unroll 8
        for (int c = 0; c < CCHUNK; ++c) {
            const int t = cnt[(size_t)c * N_NODES + i];
            cnt[(size_t)c * N_NODES + i] = (unsigned short)run;  // exclusive prefix for chunk c
            run += t;
        }
        v = run + 1;   // +1 = self-loop
    }
    int s = v;
#pragma unroll
    for (int off = 1; off < 64; off <<= 1) { int u = __shfl_up(s, off); if (lane >= off) s += u; }
    if (lane == 63) wtot[wid] = s;
    __syncthreads();
    if (tid == 0) {
        int run = 0;
        for (int w = 0; w < 16; ++w) { wexc[w] = run; run += wtot[w]; }
        __hip_atomic_store(&state[bid], (1ull << 32) | (unsigned)run,
                           __ATOMIC_RELEASE, __HIP_MEMORY_SCOPE_AGENT);
    }
    __syncthreads();
    if (wid == 0) {
        int ag = 0;
        if (lane < bid) {
            unsigned long long st;
            do {
                st = __hip_atomic_load(&state[lane], __ATOMIC_ACQUIRE,
                                       __HIP_MEMORY_SCOPE_AGENT);
            } while (!(st >> 32));
            ag = (int)(st & 0xFFFFFFFFull);
        }
#pragma unroll
        for (int off = 32; off >= 1; off >>= 1) ag += __shfl_xor(ag, off);
        if (lane == 0) sbase = ag;
    }
    __syncthreads();
    if (i < N_NODES) {
        const int o = sbase + wexc[wid] + s - v;
        offs[i] = o;
        const float2 t = sd[i];
        csr[o] = pack_entry(i, __expf(leaky(t.x + t.y)));
        if (i == 0) offs[N_NODES] = ETOT;
    }
}

// ======== scatter with LDS cursors (self slot at front: +1) ========
__global__ void __launch_bounds__(BLD) k_scatter(const int* __restrict__ srcs,
                                                 const int* __restrict__ dsts,
                                                 const float2* __restrict__ sd,
                                                 const __half* __restrict__ ec,
                                                 const unsigned short* __restrict__ cnt,
                                                 const int* __restrict__ offs,
                                                 unsigned int* __restrict__ csr) {
    __shared__ int cur[NRANGE];
    int c, r;
    cr_decode(blockIdx.x, c, r);
    const int nbase = r * NRANGE;
    const unsigned short* cslice = cnt + (size_t)c * N_NODES + nbase;
    const int* oslice = offs + nbase;
    for (int i = threadIdx.x; i < NRANGE; i += BLD) cur[i] = oslice[i] + 1 + cslice[i];
    __syncthreads();
    const int e0 = c * EPC;
    for (int i = e0 + threadIdx.x; i < e0 + EPC; i += BLD) {
        const int s = srcs[i], d = dsts[i];
        const int dl = d - nbase, sl = s - nbase;
        const bool din = (unsigned)dl < NRANGE;
        const bool sin_ = (unsigned)sl < NRANGE;
        if (!din && !sin_) continue;
        const float e = __half2float(ec[i]);
        const float2 ss = sd[s], dd = sd[d];
        if (din) {   // direction s -> d
            const int pos = atomicAdd(&cur[dl], 1);
            csr[pos] = pack_entry(s, __expf(leaky(ss.x + dd.y + e)));
        }
        if (sin_) {  // direction d -> s
            const int pos = atomicAdd(&cur[sl], 1);
            csr[pos] = pack_entry(d, __expf(leaky(dd.x + ss.y + e)));
        }
    }
}

// ======== wave-per-node, 8-way jg parallel, 4-deep software pipeline ========
__global__ void __launch_bounds__(256) k_node(const int* __restrict__ offs,
                                              const unsigned int* __restrict__ csr,
                                              const __half* __restrict__ xt,
                                              float* __restrict__ out) {
    const int node = (blockIdx.x * blockDim.x + threadIdx.x) >> 6;
    const int lane = threadIdx.x & 63;
    if (node >= N_NODES) return;
    const int beg = offs[node], end = offs[node + 1];
    const int jg = lane >> 3;        // 0..7  (8-way edge parallelism)
    const int fc = lane & 7;         // 0..7  (8 halves per lane)
    float acc[8] = {0.f, 0.f, 0.f, 0.f, 0.f, 0.f, 0.f, 0.f};
    float sum = 0.f;
    int j = beg + jg;
    // 4-deep: issue 4 csr loads, then 4 independent gathers -> 4x MLP on the chain
    for (; j + 24 < end; j += 32) {
        const unsigned int e1 = csr[j];
        const unsigned int e2 = csr[j + 8];
        const unsigned int e3 = csr[j + 16];
        const unsigned int e4 = csr[j + 24];
        const uint4 h1 = *(const uint4*)(xt + (size_t)(e1 & 0xFFFFu) * F + fc * 8);
        const uint4 h2 = *(const uint4*)(xt + (size_t)(e2 & 0xFFFFu) * F + fc * 8);
        const uint4 h3 = *(const uint4*)(xt + (size_t)(e3 & 0xFFFFu) * F + fc * 8);
        const uint4 h4 = *(const uint4*)(xt + (size_t)(e4 & 0xFFFFu) * F + fc * 8);
        const float w1 = __half2float(__ushort_as_half((unsigned short)(e1 >> 16)));
        const float w2 = __half2float(__ushort_as_half((unsigned short)(e2 >> 16)));
        const float w3 = __half2float(__ushort_as_half((unsigned short)(e3 >> 16)));
        const float w4 = __half2float(__ushort_as_half((unsigned short)(e4 >> 16)));
        sum += (w1 + w2) + (w3 + w4);
        const __half2* p1 = (const __half2*)&h1;
        const __half2* p2 = (const __half2*)&h2;
        const __half2* p3 = (const __half2*)&h3;
        const __half2* p4 = (const __half2*)&h4;
#pragma unroll
        for (int k = 0; k < 4; ++k) {
            const float2 f1 = __half22float2(p1[k]);
            const float2 f2 = __half22float2(p2[k]);
            const float2 f3 = __half22float2(p3[k]);
            const float2 f4 = __half22float2(p4[k]);
            acc[2 * k]     += (w1 * f1.x + w2 * f2.x) + (w3 * f3.x + w4 * f4.x);
            acc[2 * k + 1] += (w1 * f1.y + w2 * f2.y) + (w3 * f3.y + w4 * f4.y);
        }
    }
    for (; j < end; j += 8) {
        const unsigned int ent = csr[j];
        const float w = __half2float(__ushort_as_half((unsigned short)(ent >> 16)));
        sum += w;
        const uint4 hv = *(const uint4*)(xt + (size_t)(ent & 0xFFFFu) * F + fc * 8);
        const __half2* hp = (const __half2*)&hv;
#pragma unroll
        for (int k = 0; k < 4; ++k) {
            const float2 f = __half22float2(hp[k]);
            acc[2 * k]     += w * f.x;
            acc[2 * k + 1] += w * f.y;
        }
    }
#pragma unroll
    for (int off = 8; off <= 32; off <<= 1) {
        sum += __shfl_xor(sum, off);
#pragma unroll
        for (int k = 0; k < 8; ++k) acc[k] += __shfl_xor(acc[k], off);
    }
    if (jg == 0) {
        const float inv = 1.0f / sum;
        float4* op = (float4*)(out + (size_t)node * F + fc * 8);
        op[0] = make_float4(acc[0] * inv, acc[1] * inv, acc[2] * inv, acc[3] * inv);
        op[1] = make_float4(acc[4] * inv, acc[5] * inv, acc[6] * inv, acc[7] * inv);
    }
}

extern "C" void kernel_launch(void* const* d_in, const int* in_sizes, int n_in,
                              void* d_out, int out_size, void* d_ws, size_t ws_size,
                              hipStream_t stream) {
    const float* x    = (const float*)d_in[0];
    const int*   ei   = (const int*)d_in[1];
    const float* ea   = (const float*)d_in[2];
    const float* W    = (const float*)d_in[4];
    const float* a    = (const float*)d_in[5];
    float* out = (float*)d_out;

    const int* srcs = ei;             // edge_index[0]
    const int* dsts = ei + N_EDGES;   // edge_index[1]

    char* ws = (char*)d_ws;
    size_t off = 0;
    auto alloc = [&](size_t bytes) { void* p = ws + off; off = (off + bytes + 255) & ~(size_t)255; return p; };
    __half*             xt    = (__half*)alloc((size_t)N_NODES * F * 2);     // 6.4 MB
    float2*             sd    = (float2*)alloc((size_t)N_NODES * 8);
    __half*             ec    = (__half*)alloc((size_t)N_EDGES * 2);          // 1.6 MB
    unsigned short*     cnt   = (unsigned short*)alloc((size_t)CCHUNK * N_NODES * 2);  // 6.4 MB
    int*                offs  = (int*)alloc((size_t)(N_NODES + 1) * 4);
    unsigned int*       csr   = (unsigned int*)alloc((size_t)ETOT * 4);
    unsigned long long* state = (unsigned long long*)alloc((size_t)NB_S * 8);

    k_front<<<HIST_BLKS + XT_BLKS, BLD, 0, stream>>>(x, W, a, ea, srcs, dsts, xt, sd, ec, cnt, state);
    k_scan<<<NB_S, SCAN_B, 0, stream>>>(cnt, sd, offs, csr, state);
    k_scatter<<<HIST_BLKS, BLD, 0, stream>>>(srcs, dsts, sd, ec, cnt, offs, csr);
    k_node<<<((size_t)N_NODES * 64 + 255) / 256, 256, 0, stream>>>(offs, csr, xt, out);
}

// Round 18
// 99.220 us; speedup vs baseline: 1.0357x; 1.0357x over previous
//
#include <hip/hip_runtime.h>
#include <hip/hip_fp16.h>

#define N_NODES 50000
#define N_EDGES 800000
#define ETOT    (2 * N_EDGES + N_NODES)   // 1,650,000
#define F       64
#define NEG_SLOPE 0.2f
#define SCAN_B  1024
#define NB_S    ((N_NODES + SCAN_B - 1) / SCAN_B)   // 49 scan blocks

#define RSPLIT  4
#define NRANGE  (N_NODES / RSPLIT)        // 12500 nodes -> 50 KB LDS
#define CCHUNK  64
#define EPC     (N_EDGES / CCHUNK)        // 12500 edges per chunk
#define BLD     1024

#define XT_TASKS  (N_NODES / 16)          // 3125 wave-tasks, 16 nodes each
#define HIST_BLKS (CCHUNK * RSPLIT)       // 256
#define XT_BLKS   ((XT_TASKS + 15) / 16)  // 196 blocks of 16 waves

typedef _Float16 half8 __attribute__((ext_vector_type(8)));
typedef float    f32x4 __attribute__((ext_vector_type(4)));

__device__ __forceinline__ float leaky(float v) {
    return (v > 0.f) ? v : NEG_SLOPE * v;
}
// entry = src (low16) | fp16(exp(leaky(logit))) (high16)
__device__ __forceinline__ unsigned int pack_entry(int src, float w) {
    __half h = __float2half(w);
    return (unsigned int)(unsigned short)src |
           ((unsigned int)__half_as_ushort(h) << 16);
}
// XCD-aware (chunk,range) decode: same range r -> one XCD pair.
__device__ __forceinline__ void cr_decode(int bid, int& c, int& r) {
    const int m = bid & 7;
    r = m >> 1;
    c = ((bid >> 3) << 1) | (m & 1);
}

// ======== k_front: role-split. blocks [0,256): hist+ec. [256,452): MFMA xt ========
__global__ void __launch_bounds__(BLD) k_front(const float* __restrict__ x,
                                               const float* __restrict__ W,
                                               const float* __restrict__ a,
                                               const float* __restrict__ ea,
                                               const int* __restrict__ srcs,
                                               const int* __restrict__ dsts,
                                               __half* __restrict__ xt,
                                               float2* __restrict__ sd,
                                               __half* __restrict__ ec,
                                               unsigned short* __restrict__ cnt,
                                               unsigned long long* __restrict__ state) {
    __shared__ int h[NRANGE];
    if (blockIdx.x == 0 && threadIdx.x < NB_S) state[threadIdx.x] = 0ull;

    if (blockIdx.x < HIST_BLKS) {
        // ---- histogram + fused ec (fp16) ----
        int c, r;
        cr_decode(blockIdx.x, c, r);
        const int nbase = r * NRANGE;
        for (int i = threadIdx.x; i < NRANGE; i += BLD) h[i] = 0;
        __syncthreads();
        const int e0 = c * EPC;
        for (int i = e0 + threadIdx.x; i < e0 + EPC; i += BLD) {
            const int d = dsts[i] - nbase;
            if ((unsigned)d < NRANGE) atomicAdd(&h[d], 1);
            const int s = srcs[i] - nbase;
            if ((unsigned)s < NRANGE) atomicAdd(&h[s], 1);
        }
        const int eq0 = e0 + (r * EPC) / RSPLIT;
        const int eq1 = e0 + ((r + 1) * EPC) / RSPLIT;
        for (int i = eq0 + threadIdx.x; i < eq1; i += BLD) {
            const float4* p = (const float4*)(ea + (size_t)i * 16);
            float acc = 0.f;
#pragma unroll
            for (int k = 0; k < 4; ++k) {
                float4 v = p[k];
                acc += v.x * a[128 + k * 4 + 0] + v.y * a[128 + k * 4 + 1] +
                       v.z * a[128 + k * 4 + 2] + v.w * a[128 + k * 4 + 3];
            }
            ec[i] = __float2half(acc);
        }
        __syncthreads();
        unsigned short* o = cnt + (size_t)c * N_NODES + nbase;
        for (int i = threadIdx.x; i < NRANGE; i += BLD) o[i] = (unsigned short)h[i];
    } else {
        // ---- xt = x @ W via MFMA; one wave per 16-node task ----
        const int lane = threadIdx.x & 63;
        const int task = (blockIdx.x - HIST_BLKS) * 16 + (threadIdx.x >> 6);
        if (task >= XT_TASKS) return;
        const int n0  = task * 16;
        const int r16 = lane & 15;
        const int kb  = lane >> 4;

        half8 bf[4][2];
#pragma unroll
        for (int c = 0; c < 4; ++c)
#pragma unroll
            for (int ks = 0; ks < 2; ++ks) {
                const float* wp = W + (size_t)(ks * 32 + kb * 8) * 64 + c * 16 + r16;
#pragma unroll
                for (int j = 0; j < 8; ++j) bf[c][ks][j] = (_Float16)wp[j * 64];
            }

        half8 af[2];
#pragma unroll
        for (int ks = 0; ks < 2; ++ks) {
            const float* xp = x + (size_t)(n0 + r16) * F + ks * 32 + kb * 8;
            const float4 v0 = *(const float4*)xp;
            const float4 v1 = *(const float4*)(xp + 4);
            af[ks][0] = (_Float16)v0.x; af[ks][1] = (_Float16)v0.y;
            af[ks][2] = (_Float16)v0.z; af[ks][3] = (_Float16)v0.w;
            af[ks][4] = (_Float16)v1.x; af[ks][5] = (_Float16)v1.y;
            af[ks][6] = (_Float16)v1.z; af[ks][7] = (_Float16)v1.w;
        }

        f32x4 acc[4];
#pragma unroll
        for (int c = 0; c < 4; ++c) {
            acc[c] = (f32x4){0.f, 0.f, 0.f, 0.f};
            acc[c] = __builtin_amdgcn_mfma_f32_16x16x32_f16(af[0], bf[c][0], acc[c], 0, 0, 0);
            acc[c] = __builtin_amdgcn_mfma_f32_16x16x32_f16(af[1], bf[c][1], acc[c], 0, 0, 0);
        }

        float ps[4] = {0.f, 0.f, 0.f, 0.f};
        float pd[4] = {0.f, 0.f, 0.f, 0.f};
#pragma unroll
        for (int c = 0; c < 4; ++c) {
            const float as_ = a[c * 16 + r16];
            const float ad_ = a[64 + c * 16 + r16];
#pragma unroll
            for (int r = 0; r < 4; ++r) {
                const float v = acc[c][r];
                const int n = n0 + kb * 4 + r;
                xt[(size_t)n * F + c * 16 + r16] = __float2half(v);
                ps[r] = fmaf(v, as_, ps[r]);
                pd[r] = fmaf(v, ad_, pd[r]);
            }
        }
#pragma unroll
        for (int r = 0; r < 4; ++r) {
#pragma unroll
            for (int off = 1; off <= 8; off <<= 1) {
                ps[r] += __shfl_xor(ps[r], off);
                pd[r] += __shfl_xor(pd[r], off);
            }
        }
        if (r16 == 0) {
#pragma unroll
            for (int r = 0; r < 4; ++r) sd[n0 + kb * 4 + r] = make_float2(ps[r], pd[r]);
        }
    }
}

// ======== k_scan: chunk-prefix (in-place u16) + single-level lookback node scan ====
__global__ void k_scan(unsigned short* __restrict__ cnt,
                       const float2* __restrict__ sd,
                       int* __restrict__ offs,
                       unsigned int* __restrict__ csr,
                       unsigned long long* __restrict__ state) {
    __shared__ int wtot[16];
    __shared__ int wexc[16];
    __shared__ int sbase;
    const int tid = threadIdx.x, lane = tid & 63, wid = tid >> 6;
    const int bid = blockIdx.x;
    const int i = bid * SCAN_B + tid;
    int v = 0;
    if (i < N_NODES) {
        int run = 0;
#pragma unroll 8
        for (int c = 0; c < CCHUNK; ++c) {
            const int t = cnt[(size_t)c * N_NODES + i];
            cnt[(size_t)c * N_NODES + i] = (unsigned short)run;  // exclusive prefix for chunk c
            run += t;
        }
        v = run + 1;   // +1 = self-loop
    }
    int s = v;
#pragma unroll
    for (int off = 1; off < 64; off <<= 1) { int u = __shfl_up(s, off); if (lane >= off) s += u; }
    if (lane == 63) wtot[wid] = s;
    __syncthreads();
    if (tid == 0) {
        int run = 0;
        for (int w = 0; w < 16; ++w) { wexc[w] = run; run += wtot[w]; }
        __hip_atomic_store(&state[bid], (1ull << 32) | (unsigned)run,
                           __ATOMIC_RELEASE, __HIP_MEMORY_SCOPE_AGENT);
    }
    __syncthreads();
    if (wid == 0) {
        int ag = 0;
        if (lane < bid) {
            unsigned long long st;
            do {
                st = __hip_atomic_load(&state[lane], __ATOMIC_ACQUIRE,
                                       __HIP_MEMORY_SCOPE_AGENT);
            } while (!(st >> 32));
            ag = (int)(st & 0xFFFFFFFFull);
        }
#pragma unroll
        for (int off = 32; off >= 1; off >>= 1) ag += __shfl_xor(ag, off);
        if (lane == 0) sbase = ag;
    }
    __syncthreads();
    if (i < N_NODES) {
        const int o = sbase + wexc[wid] + s - v;
        offs[i] = o;
        const float2 t = sd[i];
        csr[o] = pack_entry(i, __expf(leaky(t.x + t.y)));
        if (i == 0) offs[N_NODES] = ETOT;
    }
}

// ======== scatter with LDS cursors (self slot at front: +1) ========
__global__ void __launch_bounds__(BLD) k_scatter(const int* __restrict__ srcs,
                                                 const int* __restrict__ dsts,
                                                 const float2* __restrict__ sd,
                                                 const __half* __restrict__ ec,
                                                 const unsigned short* __restrict__ cnt,
                                                 const int* __restrict__ offs,
                                                 unsigned int* __restrict__ csr) {
    __shared__ int cur[NRANGE];
    int c, r;
    cr_decode(blockIdx.x, c, r);
    const int nbase = r * NRANGE;
    const unsigned short* cslice = cnt + (size_t)c * N_NODES + nbase;
    const int* oslice = offs + nbase;
    for (int i = threadIdx.x; i < NRANGE; i += BLD) cur[i] = oslice[i] + 1 + cslice[i];
    __syncthreads();
    const int e0 = c * EPC;
    for (int i = e0 + threadIdx.x; i < e0 + EPC; i += BLD) {
        const int s = srcs[i], d = dsts[i];
        const int dl = d - nbase, sl = s - nbase;
        const bool din = (unsigned)dl < NRANGE;
        const bool sin_ = (unsigned)sl < NRANGE;
        if (!din && !sin_) continue;
        const float e = __half2float(ec[i]);
        const float2 ss = sd[s], dd = sd[d];
        if (din) {   // direction s -> d
            const int pos = atomicAdd(&cur[dl], 1);
            csr[pos] = pack_entry(s, __expf(leaky(ss.x + dd.y + e)));
        }
        if (sin_) {  // direction d -> s
            const int pos = atomicAdd(&cur[sl], 1);
            csr[pos] = pack_entry(d, __expf(leaky(dd.x + ss.y + e)));
        }
    }
}

// ======== wave-per-node, 8-way jg parallel, 2-deep software pipeline ========
__global__ void __launch_bounds__(256) k_node(const int* __restrict__ offs,
                                              const unsigned int* __restrict__ csr,
                                              const __half* __restrict__ xt,
                                              float* __restrict__ out) {
    const int node = (blockIdx.x * blockDim.x + threadIdx.x) >> 6;
    const int lane = threadIdx.x & 63;
    if (node >= N_NODES) return;
    const int beg = offs[node], end = offs[node + 1];
    const int jg = lane >> 3;        // 0..7  (8-way edge parallelism)
    const int fc = lane & 7;         // 0..7  (8 halves per lane)
    float acc[8] = {0.f, 0.f, 0.f, 0.f, 0.f, 0.f, 0.f, 0.f};
    float sum = 0.f;
    int j = beg + jg;
    // pairwise: issue both csr loads, then both gathers -> 2x MLP on the chain
    for (; j + 8 < end; j += 16) {
        const unsigned int e1 = csr[j];
        const unsigned int e2 = csr[j + 8];
        const float w1 = __half2float(__ushort_as_half((unsigned short)(e1 >> 16)));
        const float w2 = __half2float(__ushort_as_half((unsigned short)(e2 >> 16)));
        const uint4 h1 = *(const uint4*)(xt + (size_t)(e1 & 0xFFFFu) * F + fc * 8);
        const uint4 h2 = *(const uint4*)(xt + (size_t)(e2 & 0xFFFFu) * F + fc * 8);
        sum += w1 + w2;
        const __half2* p1 = (const __half2*)&h1;
        const __half2* p2 = (const __half2*)&h2;
#pragma unroll
        for (int k = 0; k < 4; ++k) {
            const float2 f1 = __half22float2(p1[k]);
            const float2 f2 = __half22float2(p2[k]);
            acc[2 * k]     += w1 * f1.x + w2 * f2.x;
            acc[2 * k + 1] += w1 * f1.y + w2 * f2.y;
        }
    }
    if (j < end) {
        const unsigned int ent = csr[j];
        const float w = __half2float(__ushort_as_half((unsigned short)(ent >> 16)));
        sum += w;
        const uint4 hv = *(const uint4*)(xt + (size_t)(ent & 0xFFFFu) * F + fc * 8);
        const __half2* hp = (const __half2*)&hv;
#pragma unroll
        for (int k = 0; k < 4; ++k) {
            const float2 f = __half22float2(hp[k]);
            acc[2 * k]     += w * f.x;
            acc[2 * k + 1] += w * f.y;
        }
    }
#pragma unroll
    for (int off = 8; off <= 32; off <<= 1) {
        sum += __shfl_xor(sum, off);
#pragma unroll
        for (int k = 0; k < 8; ++k) acc[k] += __shfl_xor(acc[k], off);
    }
    if (jg == 0) {
        const float inv = 1.0f / sum;
        float4* op = (float4*)(out + (size_t)node * F + fc * 8);
        op[0] = make_float4(acc[0] * inv, acc[1] * inv, acc[2] * inv, acc[3] * inv);
        op[1] = make_float4(acc[4] * inv, acc[5] * inv, acc[6] * inv, acc[7] * inv);
    }
}

extern "C" void kernel_launch(void* const* d_in, const int* in_sizes, int n_in,
                              void* d_out, int out_size, void* d_ws, size_t ws_size,
                              hipStream_t stream) {
    const float* x    = (const float*)d_in[0];
    const int*   ei   = (const int*)d_in[1];
    const float* ea   = (const float*)d_in[2];
    const float* W    = (const float*)d_in[4];
    const float* a    = (const float*)d_in[5];
    float* out = (float*)d_out;

    const int* srcs = ei;             // edge_index[0]
    const int* dsts = ei + N_EDGES;   // edge_index[1]

    char* ws = (char*)d_ws;
    size_t off = 0;
    auto alloc = [&](size_t bytes) { void* p = ws + off; off = (off + bytes + 255) & ~(size_t)255; return p; };
    __half*             xt    = (__half*)alloc((size_t)N_NODES * F * 2);     // 6.4 MB
    float2*             sd    = (float2*)alloc((size_t)N_NODES * 8);
    __half*             ec    = (__half*)alloc((size_t)N_EDGES * 2);          // 1.6 MB
    unsigned short*     cnt   = (unsigned short*)alloc((size_t)CCHUNK * N_NODES * 2);  // 6.4 MB
    int*                offs  = (int*)alloc((size_t)(N_NODES + 1) * 4);
    unsigned int*       csr   = (unsigned int*)alloc((size_t)ETOT * 4);
    unsigned long long* state = (unsigned long long*)alloc((size_t)NB_S * 8);

    k_front<<<HIST_BLKS + XT_BLKS, BLD, 0, stream>>>(x, W, a, ea, srcs, dsts, xt, sd, ec, cnt, state);
    k_scan<<<NB_S, SCAN_B, 0, stream>>>(cnt, sd, offs, csr, state);
    k_scatter<<<HIST_BLKS, BLD, 0, stream>>>(srcs, dsts, sd, ec, cnt, offs, csr);
    k_node<<<((size_t)N_NODES * 64 + 255) / 256, 256, 0, stream>>>(offs, csr, xt, out);
}